// Round 11
// baseline (253.667 us; speedup 1.0000x reference)
//
#include <hip/hip_runtime.h>

// B=4, T=2048, D=1024, H=16, hd=64. Inputs/output fp32; internal bf16 MFMA.
// R21: attn occupancy fix. Counters: attn is #1 (68us) at 27% occupancy —
// an intrinsic DECAY profile: 1024 blocks (work 2..32) all dispatch at t=0,
// 4/CU by LDS, no replacements -> CUs drain 4->1 resident blocks.
// Restructure: 64-row q-tiles (wave=16q), each block runs TWO jobs
// sequentially: tile (31-g) then tile g -> cost (32-g)+(g+1)=33 for EVERY
// block (perfect static balance, same grid=1024, no doubled reg state).
// Ps shrinks to 4x16xQS -> LDS 26.6KB -> 6 blocks/CU (was 4). Job A's last
// prefetch slot bridges to job B's tile 0. Fragment indexing = verified v10
// specialized to single nt/mg (P row = col; epilogue rows wid*16+quad*4+r).
// gemm256 (R20) and prep unchanged (controls).

typedef __bf16 bf16;
typedef __attribute__((ext_vector_type(8))) __bf16 bf16x8;
typedef __attribute__((ext_vector_type(4))) __bf16 bf16x4;
typedef __attribute__((ext_vector_type(4))) float f4;

__device__ __forceinline__ void stage16(const bf16* g, bf16* l) {
    __builtin_amdgcn_global_load_lds((const __attribute__((address_space(1))) void*)g,
                                     (__attribute__((address_space(3))) void*)l,
                                     16, 0, 0);
}

__device__ __forceinline__ float fast_exp2(float x) {
    float r;
    asm("v_exp_f32 %0, %1" : "=v"(r) : "v"(x));
    return r;
}

// ---------------- fused prep: cast x + transpose both weights -------------
__global__ __launch_bounds__(256)
void prep(const float* __restrict__ x, bf16* __restrict__ xb,
          const float* __restrict__ Wa, bf16* __restrict__ WtA,
          const float* __restrict__ Wp, bf16* __restrict__ WtP)
{
    __shared__ bf16 tile[64][65];
    int bid = blockIdx.x;
    int tid = threadIdx.x;
    if (bid < 8192) {
        int i = bid * 256 + tid;
        float4 v = ((const float4*)x)[i];
        bf16x4 o = { (bf16)v.x, (bf16)v.y, (bf16)v.z, (bf16)v.w };
        *(bf16x4*)&xb[i * 4] = o;
        return;
    }
    const float* src; bf16* dst; int R, C, c0, r0;
    if (bid < 8960) {
        int t = bid - 8192;                // 48 x 16 tiles
        src = Wa; dst = WtA; R = 1024; C = 3072;
        c0 = (t % 48) * 64; r0 = (t / 48) * 64;
    } else {
        int t = bid - 8960;                // 16 x 16 tiles
        src = Wp; dst = WtP; R = 1024; C = 1024;
        c0 = (t % 16) * 64; r0 = (t / 16) * 64;
    }
    for (int i = tid; i < 64 * 64; i += 256) {
        int r = i >> 6, c = i & 63;
        tile[r][c] = (bf16)src[(long)(r0 + r) * C + c0 + c];
    }
    __syncthreads();
    for (int i = tid; i < 64 * 64; i += 256) {
        int r = i >> 6, c = i & 63;
        dst[(long)(c0 + r) * R + r0 + c] = tile[c][r];
    }
}

// ---------------- GEMM 128x256, 2 barriers/K-tile (T1..T5) ----------------
#define VMW6 asm volatile("s_waitcnt vmcnt(6)" ::: "memory")
#define VMW0 asm volatile("s_waitcnt vmcnt(0)" ::: "memory")
#define CLOB asm volatile("" ::: "memory")
#define BARR __builtin_amdgcn_s_barrier()

template <typename OutT>
__global__ __launch_bounds__(512)
void gemm256(const bf16* __restrict__ A, const bf16* __restrict__ Bt,
             OutT* __restrict__ C, int lda, int ldb, int ldc, int K)
{
    extern __shared__ bf16 lds[];
    bf16* Asl = lds;                  // [2][128][64]
    bf16* Bsl = lds + 16384;          // [2][256][64]
    int tid = threadIdx.x;
    int lane = tid & 63, wid = tid >> 6;
    int wm = wid >> 2, wn = wid & 3;
    int quad = lane >> 4, col = lane & 15;

    int nwg = gridDim.x * gridDim.y;
    int bid = blockIdx.y * gridDim.x + blockIdx.x;
    int swz = (bid & 7) * (nwg >> 3) + (bid >> 3);
    int bx = swz % gridDim.x, by = swz / gridDim.x;
    int m0 = by * 128, n0 = bx * 256;

    int NT = K >> 6;
    int srow = wid * 8 + (lane >> 3);
    int lincol = (lane & 7) * 8;
    int swcol  = ((lane & 7) ^ ((lane >> 3) & 7)) * 8;
    int xorv = (col & 7) << 4;
    int ke0 = ((quad * 16) ^ xorv) >> 1;
    int ke1 = ((quad * 16 + 64) ^ xorv) >> 1;

    f4 acc[4][4];
    #pragma unroll
    for (int mi = 0; mi < 4; ++mi)
        #pragma unroll
        for (int ni = 0; ni < 4; ++ni)
            acc[mi][ni] = (f4){0.f, 0.f, 0.f, 0.f};

    #define STG_HALF(mat, rb, ld, ts, dstb) do {                                \
        _Pragma("unroll")                                                       \
        for (int _i = 0; _i < 2; ++_i)                                          \
            stage16((mat) + (long)((rb) + _i * 64 + srow) * (ld) + (ts) * 64 + swcol, \
                    (dstb) + (_i * 64 + srow) * 64 + lincol);                   \
    } while (0)
    #define STGA(ts) STG_HALF(A, m0, lda, (ts), Asl + ((ts) & 1) * 8192)
    #define STGB(ts) do { bf16* _d = Bsl + ((ts) & 1) * 16384;                  \
        STG_HALF(Bt, n0,       ldb, (ts), _d);                                  \
        STG_HALF(Bt, n0 + 128, ldb, (ts), _d + 8192); } while (0)

    bf16x8 a[2][2], bb[4][2];
    #define RD_A(mp) do { _Pragma("unroll")                                     \
        for (int _m = 0; _m < 2; ++_m) {                                        \
            int _r = ab + ((mp) * 2 + _m) * 1024;                               \
            a[_m][0] = *(const bf16x8*)&Asl[_r + ke0];                          \
            a[_m][1] = *(const bf16x8*)&Asl[_r + ke1]; } } while (0)
    #define RD_B(np) do { _Pragma("unroll")                                     \
        for (int _n = 0; _n < 2; ++_n) {                                        \
            int _r = bbo + ((np) * 2 + _n) * 1024;                              \
            bb[(np)*2+_n][0] = *(const bf16x8*)&Bsl[_r + ke0];                  \
            bb[(np)*2+_n][1] = *(const bf16x8*)&Bsl[_r + ke1]; } } while (0)
    #define MM(mp, np) do { __builtin_amdgcn_s_setprio(1);                      \
        _Pragma("unroll")                                                       \
        for (int _m = 0; _m < 2; ++_m)                                          \
            _Pragma("unroll")                                                   \
            for (int _n = 0; _n < 2; ++_n)                                      \
                _Pragma("unroll")                                               \
                for (int kk = 0; kk < 2; ++kk)                                  \
                    acc[(mp)*2+_m][(np)*2+_n] =                                 \
                        __builtin_amdgcn_mfma_f32_16x16x32_bf16(                \
                            a[_m][kk], bb[(np)*2+_n][kk],                       \
                            acc[(mp)*2+_m][(np)*2+_n], 0, 0, 0);                \
        __builtin_amdgcn_s_setprio(0); } while (0)

    STGB(0); STGA(0); STGB(1); STGA(1);
    VMW6; CLOB; BARR; CLOB;

    for (int t = 0; t < NT; ++t) {
        int b = t & 1;
        int ab  = b * 8192  + (wm * 64 + col) * 64;
        int bbo = b * 16384 + (wn * 64 + col) * 64;
        RD_A(0); RD_B(0); RD_B(1);
        CLOB;
        MM(0, 0); MM(0, 1);
        CLOB; BARR; CLOB;
        RD_A(1);
        if (t + 2 < NT) STGB(t + 2);
        CLOB;
        MM(1, 1); MM(1, 0);
        if (t + 2 < NT) { STGA(t + 2); VMW6; }
        else if (t + 1 < NT) { VMW0; }
        CLOB; BARR;
    }
    #undef STG_HALF
    #undef STGA
    #undef STGB
    #undef RD_A
    #undef RD_B
    #undef MM

    #pragma unroll
    for (int mi = 0; mi < 4; ++mi) {
        int rbase = m0 + wm * 64 + mi * 16 + quad * 4;
        #pragma unroll
        for (int ni = 0; ni < 4; ++ni) {
            int cc = n0 + wn * 64 + ni * 16 + col;
            #pragma unroll
            for (int r = 0; r < 4; ++r)
                C[(long)(rbase + r) * ldc + cc] = (OutT)acc[mi][ni][r];
        }
    }
}

// ---------------- MFMA flash attention, v11 (paired 64-row q-tiles) -------
// Block = (bh, pair g): job A = q-tile 31-g (nkA=32-g), job B = q-tile g
// (nkB=g+1); total 33 k-tile iters for EVERY block. 4 waves x 16 q-rows.
// Per k-tile: S^T = K Q^T per 16-row k-chunk -> softmax -> P[q][k] in LDS
// -> O += P V, l += P*1 via MFMA. Diag mask only at kt == nk-1.
#define QS 72
#define C_SL 0.18033688011112042f   // 0.125 * log2(e)

__device__ __forceinline__ int vsw(int d, int k) {
    return d * 64 + ((((k >> 3) ^ (d & 7) ^ ((d >> 3) & 7)) & 7) << 3) + (k & 7);
}

__device__ __forceinline__ void attn_tile(
    const bf16x8 (&aq)[2], f4 (&of)[4], f4 &lac, const bf16x8 &bones,
    bf16* Pw, const bf16* Ks, const bf16* Vt,
    int quad, int col, int qg, int k0, bool diag)
{
    // S^T = K Q^T per 16-row k-chunk; st[r] = S[k0+mt*16+quad*4+r][q=qg]
    #pragma unroll
    for (int mt = 0; mt < 4; ++mt) {
        bf16x8 ak0 = *(const bf16x8*)&Ks[(mt * 16 + col) * QS + quad * 8];
        bf16x8 ak1 = *(const bf16x8*)&Ks[(mt * 16 + col) * QS + 32 + quad * 8];
        f4 z = (f4){0.f, 0.f, 0.f, 0.f};
        __builtin_amdgcn_s_setprio(1);
        z = __builtin_amdgcn_mfma_f32_16x16x32_bf16(ak0, aq[0], z, 0, 0, 0);
        f4 st = __builtin_amdgcn_mfma_f32_16x16x32_bf16(ak1, aq[1], z, 0, 0, 0);
        __builtin_amdgcn_s_setprio(0);
        bf16x4 pk;
        if (diag) {
            #pragma unroll
            for (int r = 0; r < 4; ++r) {
                float arg = fmaf(st[r], C_SL, -16.f);
                if ((k0 + mt * 16 + quad * 4 + r) > qg) arg = -1e30f;
                pk[r] = (bf16)fast_exp2(arg);
            }
        } else {
            #pragma unroll
            for (int r = 0; r < 4; ++r)
                pk[r] = (bf16)fast_exp2(fmaf(st[r], C_SL, -16.f));
        }
        *(bf16x4*)&Pw[col * QS + mt * 16 + quad * 4] = pk;   // P[q=col][k]
    }
    // P readback (wave-private, no barrier)
    bf16x8 ap0 = *(const bf16x8*)&Pw[col * QS + quad * 8];
    bf16x8 ap1 = *(const bf16x8*)&Pw[col * QS + 32 + quad * 8];
    // O += P V: each V frag pair read once, feeds 2 MFMAs
    #pragma unroll
    for (int nd = 0; nd < 4; ++nd) {
        bf16x8 bv0 = *(const bf16x8*)&Vt[vsw(nd * 16 + col, quad * 8)];
        bf16x8 bv1 = *(const bf16x8*)&Vt[vsw(nd * 16 + col, 32 + quad * 8)];
        __builtin_amdgcn_s_setprio(1);
        of[nd] = __builtin_amdgcn_mfma_f32_16x16x32_bf16(ap0, bv0, of[nd], 0, 0, 0);
        of[nd] = __builtin_amdgcn_mfma_f32_16x16x32_bf16(ap1, bv1, of[nd], 0, 0, 0);
        __builtin_amdgcn_s_setprio(0);
    }
    __builtin_amdgcn_s_setprio(1);
    lac = __builtin_amdgcn_mfma_f32_16x16x32_bf16(ap0, bones, lac, 0, 0, 0);
    lac = __builtin_amdgcn_mfma_f32_16x16x32_bf16(ap1, bones, lac, 0, 0, 0);
    __builtin_amdgcn_s_setprio(0);
}

__global__ __launch_bounds__(256)
void attn_mfma(bf16* __restrict__ qkv)
{
    __shared__ bf16 Ks[64 * QS];        //  9.2 KB
    __shared__ bf16 Vt[64 * 64];        //  8.0 KB (vsw-swizzled)
    __shared__ bf16 Ps[4 * 16 * QS];    //  9.2 KB  -> total 26.6 KB, 6 blk/CU
    const int T = 2048, D3 = 3072;
    int tid = threadIdx.x;
    int lane = tid & 63, wid = tid >> 6;
    int quad = lane >> 4, col = lane & 15;
    int bh = blockIdx.x & 63;
    int g  = blockIdx.x >> 6;            // pair index 0..15
    int b = bh >> 4, h = bh & 15;
    long base = (long)b * T * D3 + h * 64;
    int jA = 31 - g, jB = g;             // big job first
    int nkA = jA + 1, nkB = jB + 1;      // nkA + nkB = 33
    int srow = tid >> 2, dseg = (tid & 3) * 16;     // K staging map (64x64)
    int kg4 = (tid >> 4) * 4, dg4 = (tid & 15) * 4; // V staging map (4k x 4d)
    bf16* Pw = &Ps[wid * 16 * QS];
    int q0wA = jA * 64 + wid * 16, q0wB = jB * 64 + wid * 16;

    // Q B-frags for BOTH jobs: lane holds Q[q=q0w+col][d=quad*8+j+32*ch]
    bf16x8 aqA[2], aqB[2];
    {
        const bf16* gq = &qkv[base + (long)(q0wA + col) * D3 + quad * 8];
        aqA[0] = *(const bf16x8*)gq;
        aqA[1] = *(const bf16x8*)(gq + 32);
        const bf16* gq2 = &qkv[base + (long)(q0wB + col) * D3 + quad * 8];
        aqB[0] = *(const bf16x8*)gq2;
        aqB[1] = *(const bf16x8*)(gq2 + 32);
    }
    bf16 one1 = (bf16)1.0f;
    bf16x8 bones = {one1, one1, one1, one1, one1, one1, one1, one1};

    f4 of[4], lac;
    #pragma unroll
    for (int n = 0; n < 4; ++n) of[n] = (f4){0.f, 0.f, 0.f, 0.f};
    lac = (f4){0.f, 0.f, 0.f, 0.f};

    // prefetch k-tile 0
    const bf16* gK = &qkv[base + (long)srow * D3 + 1024 + dseg];
    bf16x8 kr0 = *(const bf16x8*)gK;
    bf16x8 kr1 = *(const bf16x8*)(gK + 8);
    const bf16* gV = &qkv[base + (long)kg4 * D3 + 2048 + dg4];
    bf16x4 vr[4];
    #pragma unroll
    for (int j = 0; j < 4; ++j) vr[j] = *(const bf16x4*)(gV + (long)j * D3);

    // ---- job A (nkA tiles); last prefetch bridges to job B's tile 0 ----
    for (int kt = 0; kt < nkA; ++kt) {
        __syncthreads();                 // prior iter's LDS reads done
        *(bf16x8*)&Ks[srow * QS + dseg]     = kr0;
        *(bf16x8*)&Ks[srow * QS + dseg + 8] = kr1;
        #pragma unroll
        for (int i = 0; i < 4; ++i) {    // 4x4 in-register transpose
            bf16x4 c = { vr[0][i], vr[1][i], vr[2][i], vr[3][i] };
            *(bf16x4*)&Vt[vsw(dg4 + i, kg4)] = c;
        }
        {   // next tile, or job B's tile 0 on the last iteration
            int nxt = (kt + 1 < nkA) ? kt + 1 : 0;
            const bf16* gKn = &qkv[base + (long)(nxt * 64 + srow) * D3 + 1024 + dseg];
            kr0 = *(const bf16x8*)gKn;
            kr1 = *(const bf16x8*)(gKn + 8);
            const bf16* gVn = &qkv[base + (long)(nxt * 64 + kg4) * D3 + 2048 + dg4];
            #pragma unroll
            for (int j = 0; j < 4; ++j) vr[j] = *(const bf16x4*)(gVn + (long)j * D3);
        }
        __syncthreads();
        attn_tile(aqA, of, lac, bones, Pw, Ks, Vt, quad, col,
                  q0wA + col, kt * 64, kt == nkA - 1);
    }
    // epilogue A: y rows q0wA + quad*4 + r
    #pragma unroll
    for (int r = 0; r < 4; ++r) {
        float inv = 1.f / lac[r];
        long yoff = base + (long)(q0wA + quad * 4 + r) * D3;
        #pragma unroll
        for (int nd = 0; nd < 4; ++nd)
            qkv[yoff + nd * 16 + col] = (bf16)(of[nd][r] * inv);
    }
    #pragma unroll
    for (int n = 0; n < 4; ++n) of[n] = (f4){0.f, 0.f, 0.f, 0.f};
    lac = (f4){0.f, 0.f, 0.f, 0.f};

    // ---- job B (nkB tiles) ----
    for (int kt = 0; kt < nkB; ++kt) {
        __syncthreads();
        *(bf16x8*)&Ks[srow * QS + dseg]     = kr0;
        *(bf16x8*)&Ks[srow * QS + dseg + 8] = kr1;
        #pragma unroll
        for (int i = 0; i < 4; ++i) {
            bf16x4 c = { vr[0][i], vr[1][i], vr[2][i], vr[3][i] };
            *(bf16x4*)&Vt[vsw(dg4 + i, kg4)] = c;
        }
        if (kt + 1 < nkB) {
            const bf16* gKn = &qkv[base + (long)((kt + 1) * 64 + srow) * D3 + 1024 + dseg];
            kr0 = *(const bf16x8*)gKn;
            kr1 = *(const bf16x8*)(gKn + 8);
            const bf16* gVn = &qkv[base + (long)((kt + 1) * 64 + kg4) * D3 + 2048 + dg4];
            #pragma unroll
            for (int j = 0; j < 4; ++j) vr[j] = *(const bf16x4*)(gVn + (long)j * D3);
        }
        __syncthreads();
        attn_tile(aqB, of, lac, bones, Pw, Ks, Vt, quad, col,
                  q0wB + col, kt * 64, kt == nkB - 1);
    }
    // epilogue B
    #pragma unroll
    for (int r = 0; r < 4; ++r) {
        float inv = 1.f / lac[r];
        long yoff = base + (long)(q0wB + quad * 4 + r) * D3;
        #pragma unroll
        for (int nd = 0; nd < 4; ++nd)
            qkv[yoff + nd * 16 + col] = (bf16)(of[nd][r] * inv);
    }
}

// --------------------------------------------------------------------------
extern "C" void kernel_launch(void* const* d_in, const int* in_sizes, int n_in,
                              void* d_out, int out_size, void* d_ws, size_t ws_size,
                              hipStream_t stream) {
    const float* x      = (const float*)d_in[0];  // [8192,1024] fp32
    const float* W_attn = (const float*)d_in[1];  // [1024,3072] fp32
    const float* W_proj = (const float*)d_in[2];  // [1024,1024] fp32
    float* out = (float*)d_out;                   // [8192,1024] fp32

    // ws layout (58.7 MB): qkv | WtA | WtP
    bf16* qkv = (bf16*)d_ws;                         // [8192,3072]  50.3 MB
    bf16* WtA = qkv + (size_t)8192 * 3072;           // [3072,1024]   6.3 MB
    bf16* WtP = WtA + (size_t)3072 * 1024;           // [1024,1024]   2.1 MB
    bf16* xb = (bf16*)d_out;   // bf16 x staged in d_out; dead before gemm2

    static bool attr_set = false;
    if (!attr_set) {
        hipFuncSetAttribute((const void*)gemm256<bf16>,
                            hipFuncAttributeMaxDynamicSharedMemorySize, 98304);
        hipFuncSetAttribute((const void*)gemm256<float>,
                            hipFuncAttributeMaxDynamicSharedMemorySize, 98304);
        attr_set = true;
    }

    // fused prep: cast x (8192 blocks) + transpose W_attn (768) + W_proj (256)
    prep<<<9216, 256, 0, stream>>>(x, xb, W_attn, WtA, W_proj, WtP);
    // qkv = xb @ W_attn  (bf16 out): 128x256 tiles, grid 12x64 = 768 = 3*256
    gemm256<bf16><<<dim3(12, 64), 512, 98304, stream>>>(xb, WtA, qkv,
                                                        1024, 1024, 3072, 1024);
    // MFMA flash attention; y written into qkv's Q columns (paired 64-row tiles)
    attn_mfma<<<1024, 256, 0, stream>>>(qkv);
    // out = y @ W_proj: 128x256 tiles, grid 4x64 = 256 = exactly 1 wave
    gemm256<float><<<dim3(4, 64), 512, 98304, stream>>>(qkv, WtP, out,
                                                        3072, 1024, 1024, 1024);
}

// Round 12
// 236.654 us; speedup vs baseline: 1.0719x; 1.0719x over previous
//
#include <hip/hip_runtime.h>

// B=4, T=2048, D=1024, H=16, hd=64. Inputs/output fp32; internal bf16 MFMA.
// R22: (a) REVERT attn to R20-verified v10 (R21's 64-row pairing regressed:
// occupancy fell 27->24, conflicts 8.9M->14.1M, FETCH +31% from halved
// staging amortization). (b) gemm1 -> 256x256 8-phase m201-grain kernel:
// per K-tile 4 phases x {ds-read subtile + stage ONE half-tile + 2 barriers
// + 16 MFMA under setprio}; counted vmcnt(6) ONLY at phases 4/8 (3
// half-tiles in flight); stage rotation ph1:A1(t+1) ph2:B0(t+2) ph3:B1(t+2)
// ph4:A0(t+2)+VMW6 ph5:A1(t+2) ph6:B0(t+3) ph7:B1(t+3) ph8:A0(t+3)+VMW6 —
// every stage lands strictly after its region's last reader passed a
// barrier; last iteration drains with vmcnt(0). Swizzle/read formulas
// identical to the 0-conflict R19 kernel. gemm2 stays on the verified
// 128x256 kernel (grid 4x64 = 256 = exactly 1 full wave).

typedef __bf16 bf16;
typedef __attribute__((ext_vector_type(8))) __bf16 bf16x8;
typedef __attribute__((ext_vector_type(4))) __bf16 bf16x4;
typedef __attribute__((ext_vector_type(4))) float f4;

__device__ __forceinline__ void stage16(const bf16* g, bf16* l) {
    __builtin_amdgcn_global_load_lds((const __attribute__((address_space(1))) void*)g,
                                     (__attribute__((address_space(3))) void*)l,
                                     16, 0, 0);
}

__device__ __forceinline__ float fast_exp2(float x) {
    float r;
    asm("v_exp_f32 %0, %1" : "=v"(r) : "v"(x));
    return r;
}

// ---------------- fused prep: cast x + transpose both weights -------------
__global__ __launch_bounds__(256)
void prep(const float* __restrict__ x, bf16* __restrict__ xb,
          const float* __restrict__ Wa, bf16* __restrict__ WtA,
          const float* __restrict__ Wp, bf16* __restrict__ WtP)
{
    __shared__ bf16 tile[64][65];
    int bid = blockIdx.x;
    int tid = threadIdx.x;
    if (bid < 8192) {
        int i = bid * 256 + tid;
        float4 v = ((const float4*)x)[i];
        bf16x4 o = { (bf16)v.x, (bf16)v.y, (bf16)v.z, (bf16)v.w };
        *(bf16x4*)&xb[i * 4] = o;
        return;
    }
    const float* src; bf16* dst; int R, C, c0, r0;
    if (bid < 8960) {
        int t = bid - 8192;                // 48 x 16 tiles
        src = Wa; dst = WtA; R = 1024; C = 3072;
        c0 = (t % 48) * 64; r0 = (t / 48) * 64;
    } else {
        int t = bid - 8960;                // 16 x 16 tiles
        src = Wp; dst = WtP; R = 1024; C = 1024;
        c0 = (t % 16) * 64; r0 = (t / 16) * 64;
    }
    for (int i = tid; i < 64 * 64; i += 256) {
        int r = i >> 6, c = i & 63;
        tile[r][c] = (bf16)src[(long)(r0 + r) * C + c0 + c];
    }
    __syncthreads();
    for (int i = tid; i < 64 * 64; i += 256) {
        int r = i >> 6, c = i & 63;
        dst[(long)(c0 + r) * R + r0 + c] = tile[c][r];
    }
}

#define VMW6 asm volatile("s_waitcnt vmcnt(6)" ::: "memory")
#define VMW0 asm volatile("s_waitcnt vmcnt(0)" ::: "memory")
#define CLOB asm volatile("" ::: "memory")
#define BARR __builtin_amdgcn_s_barrier()

// ---------------- GEMM 256x256, 8-phase m201-grain (T1..T5) ---------------
// C[M,N] = A[M,K] x Bt[N,K]^T, bf16 out. 512 thr = 8 waves (2M x 4N);
// per-wave 128x64 out (8x4 frags). BK=64; LDS 128KB: Asl[2][256][64],
// Bsl[2][256][64]; involution source-swizzle + XOR reads (0-conflict).
__global__ __launch_bounds__(512)
void gemm256sq(const bf16* __restrict__ A, const bf16* __restrict__ Bt,
               bf16* __restrict__ C, int lda, int ldb, int ldc, int K)
{
    extern __shared__ bf16 lds[];
    bf16* Asl = lds;                  // [2][256][64] 64KB
    bf16* Bsl = lds + 32768;          // [2][256][64] 64KB
    int tid = threadIdx.x;
    int lane = tid & 63, wid = tid >> 6;
    int wm = wid >> 2, wn = wid & 3;
    int quad = lane >> 4, col = lane & 15;

    int nwg = gridDim.x * gridDim.y;
    int bid = blockIdx.y * gridDim.x + blockIdx.x;
    int swz = (bid & 7) * (nwg >> 3) + (bid >> 3);
    int bx = swz % gridDim.x, by = swz / gridDim.x;
    int m0 = by * 256, n0 = bx * 256;

    int NT = K >> 6;                  // even (K=1024 -> 16)
    int srow = wid * 8 + (lane >> 3);
    int lincol = (lane & 7) * 8;
    int swcol  = ((lane & 7) ^ ((lane >> 3) & 7)) * 8;
    int xorv = (col & 7) << 4;
    int ke0 = ((quad * 16) ^ xorv) >> 1;
    int ke1 = ((quad * 16 + 64) ^ xorv) >> 1;

    f4 acc[8][4];
    #pragma unroll
    for (int mi = 0; mi < 8; ++mi)
        #pragma unroll
        for (int ni = 0; ni < 4; ++ni)
            acc[mi][ni] = (f4){0.f, 0.f, 0.f, 0.f};

    // stage half h (0/1) of K-tile ts (skipped past NT)
    #define STGH(mat, rb, ld, base0, h, ts) do { if ((ts) < NT) {               \
        bf16* _d = (base0) + (((ts) & 1) * 2 + (h)) * 8192;                     \
        _Pragma("unroll")                                                       \
        for (int _i = 0; _i < 2; ++_i)                                          \
            stage16((mat) + (long)((rb) + (h) * 128 + _i * 64 + srow) * (ld) + (ts) * 64 + swcol, \
                    _d + (_i * 64 + srow) * 64 + lincol); } } while (0)
    #define SA(h, ts) STGH(A,  m0, lda, Asl, h, ts)
    #define SB(h, ts) STGH(Bt, n0, ldb, Bsl, h, ts)

    bf16x8 a[4][2], b0[2][2], b1[2][2];
    #define RDA(qm, bo) do { _Pragma("unroll")                                  \
        for (int _m = 0; _m < 4; ++_m) {                                        \
            int _r = (bo) + ((wm * 128 + (qm) * 64 + _m * 16 + col) << 6);      \
            a[_m][0] = *(const bf16x8*)&Asl[_r + ke0];                          \
            a[_m][1] = *(const bf16x8*)&Asl[_r + ke1]; } } while (0)
    #define RDB(arr, qn, bo) do { _Pragma("unroll")                             \
        for (int _n = 0; _n < 2; ++_n) {                                        \
            int _r = (bo) + ((wn * 64 + (qn) * 32 + _n * 16 + col) << 6);       \
            arr[_n][0] = *(const bf16x8*)&Bsl[_r + ke0];                        \
            arr[_n][1] = *(const bf16x8*)&Bsl[_r + ke1]; } } while (0)
    #define MMQ(qm, arr, qn) do { __builtin_amdgcn_s_setprio(1);                \
        _Pragma("unroll")                                                       \
        for (int _m = 0; _m < 4; ++_m)                                          \
            _Pragma("unroll")                                                   \
            for (int _n = 0; _n < 2; ++_n)                                      \
                _Pragma("unroll")                                               \
                for (int kk = 0; kk < 2; ++kk)                                  \
                    acc[(qm)*4+_m][(qn)*2+_n] =                                 \
                        __builtin_amdgcn_mfma_f32_16x16x32_bf16(                \
                            a[_m][kk], arr[_n][kk],                             \
                            acc[(qm)*4+_m][(qn)*2+_n], 0, 0, 0);                \
        __builtin_amdgcn_s_setprio(0); } while (0)

    // prologue: tile0 (4 halves) + tile1's B0,A0,B1. VMW6 -> tile0 landed.
    SB(0, 0); SA(0, 0); SB(1, 0); SA(1, 0); SB(0, 1); SA(0, 1); SB(1, 1);
    VMW6; CLOB; BARR; CLOB;

    for (int t = 0; t < NT; t += 2) {
        bool deep = (t + 3 < NT);
        // ---- tile t (buf0) ----
        // ph1: rd A0,B0; stage A1(t+1); MM(0,0)
        RDA(0, 0); RDB(b0, 0, 0);
        SA(1, t + 1);
        CLOB; BARR; CLOB; MMQ(0, b0, 0); CLOB; BARR;
        // ph2: rd B1; stage B0(t+2); MM(0,1)
        RDB(b1, 1, 0);
        SB(0, t + 2);
        CLOB; BARR; CLOB; MMQ(0, b1, 1); CLOB; BARR;
        // ph3: rd A1; stage B1(t+2); MM(1,1)
        RDA(1, 0);
        SB(1, t + 2);
        CLOB; BARR; CLOB; MMQ(1, b1, 1); CLOB; BARR;
        // ph4: stage A0(t+2); VMW -> tile t+1 landed; MM(1,0)
        SA(0, t + 2);
        if (deep) { VMW6; } else { VMW0; }
        CLOB; BARR; CLOB; MMQ(1, b0, 0); CLOB; BARR;
        // ---- tile t+1 (buf1) ----
        // ph5: rd A0,B0; stage A1(t+2); MM(0,0)
        RDA(0, 16384); RDB(b0, 0, 16384);
        SA(1, t + 2);
        CLOB; BARR; CLOB; MMQ(0, b0, 0); CLOB; BARR;
        // ph6: rd B1; stage B0(t+3); MM(0,1)
        RDB(b1, 1, 16384);
        SB(0, t + 3);
        CLOB; BARR; CLOB; MMQ(0, b1, 1); CLOB; BARR;
        // ph7: rd A1; stage B1(t+3); MM(1,1)
        RDA(1, 16384);
        SB(1, t + 3);
        CLOB; BARR; CLOB; MMQ(1, b1, 1); CLOB; BARR;
        // ph8: stage A0(t+3); VMW -> tile t+2 landed; MM(1,0)
        SA(0, t + 3);
        if (deep) { VMW6; } else { VMW0; }
        CLOB; BARR; CLOB; MMQ(1, b0, 0); CLOB; BARR;
    }
    #undef STGH
    #undef SA
    #undef SB
    #undef RDA
    #undef RDB
    #undef MMQ

    #pragma unroll
    for (int j = 0; j < 8; ++j) {
        int rbase = m0 + wm * 128 + (j >> 2) * 64 + (j & 3) * 16 + quad * 4;
        #pragma unroll
        for (int n = 0; n < 4; ++n) {
            int cc = n0 + wn * 64 + (n >> 1) * 32 + (n & 1) * 16 + col;
            #pragma unroll
            for (int r = 0; r < 4; ++r)
                C[(long)(rbase + r) * ldc + cc] = (bf16)acc[j][n][r];
        }
    }
}

// ---------------- GEMM 128x256, 2 barriers/K-tile (R20-verified) ----------
template <typename OutT>
__global__ __launch_bounds__(512)
void gemm256(const bf16* __restrict__ A, const bf16* __restrict__ Bt,
             OutT* __restrict__ C, int lda, int ldb, int ldc, int K)
{
    extern __shared__ bf16 lds[];
    bf16* Asl = lds;                  // [2][128][64]
    bf16* Bsl = lds + 16384;          // [2][256][64]
    int tid = threadIdx.x;
    int lane = tid & 63, wid = tid >> 6;
    int wm = wid >> 2, wn = wid & 3;
    int quad = lane >> 4, col = lane & 15;

    int nwg = gridDim.x * gridDim.y;
    int bid = blockIdx.y * gridDim.x + blockIdx.x;
    int swz = (bid & 7) * (nwg >> 3) + (bid >> 3);
    int bx = swz % gridDim.x, by = swz / gridDim.x;
    int m0 = by * 128, n0 = bx * 256;

    int NT = K >> 6;
    int srow = wid * 8 + (lane >> 3);
    int lincol = (lane & 7) * 8;
    int swcol  = ((lane & 7) ^ ((lane >> 3) & 7)) * 8;
    int xorv = (col & 7) << 4;
    int ke0 = ((quad * 16) ^ xorv) >> 1;
    int ke1 = ((quad * 16 + 64) ^ xorv) >> 1;

    f4 acc[4][4];
    #pragma unroll
    for (int mi = 0; mi < 4; ++mi)
        #pragma unroll
        for (int ni = 0; ni < 4; ++ni)
            acc[mi][ni] = (f4){0.f, 0.f, 0.f, 0.f};

    #define STG_HALF(mat, rb, ld, ts, dstb) do {                                \
        _Pragma("unroll")                                                       \
        for (int _i = 0; _i < 2; ++_i)                                          \
            stage16((mat) + (long)((rb) + _i * 64 + srow) * (ld) + (ts) * 64 + swcol, \
                    (dstb) + (_i * 64 + srow) * 64 + lincol);                   \
    } while (0)
    #define STGA(ts) STG_HALF(A, m0, lda, (ts), Asl + ((ts) & 1) * 8192)
    #define STGB(ts) do { bf16* _d = Bsl + ((ts) & 1) * 16384;                  \
        STG_HALF(Bt, n0,       ldb, (ts), _d);                                  \
        STG_HALF(Bt, n0 + 128, ldb, (ts), _d + 8192); } while (0)

    bf16x8 a[2][2], bb[4][2];
    #define RD_A(mp) do { _Pragma("unroll")                                     \
        for (int _m = 0; _m < 2; ++_m) {                                        \
            int _r = ab + ((mp) * 2 + _m) * 1024;                               \
            a[_m][0] = *(const bf16x8*)&Asl[_r + ke0];                          \
            a[_m][1] = *(const bf16x8*)&Asl[_r + ke1]; } } while (0)
    #define RD_B(np) do { _Pragma("unroll")                                     \
        for (int _n = 0; _n < 2; ++_n) {                                        \
            int _r = bbo + ((np) * 2 + _n) * 1024;                              \
            bb[(np)*2+_n][0] = *(const bf16x8*)&Bsl[_r + ke0];                  \
            bb[(np)*2+_n][1] = *(const bf16x8*)&Bsl[_r + ke1]; } } while (0)
    #define MM(mp, np) do { __builtin_amdgcn_s_setprio(1);                      \
        _Pragma("unroll")                                                       \
        for (int _m = 0; _m < 2; ++_m)                                          \
            _Pragma("unroll")                                                   \
            for (int _n = 0; _n < 2; ++_n)                                      \
                _Pragma("unroll")                                               \
                for (int kk = 0; kk < 2; ++kk)                                  \
                    acc[(mp)*2+_m][(np)*2+_n] =                                 \
                        __builtin_amdgcn_mfma_f32_16x16x32_bf16(                \
                            a[_m][kk], bb[(np)*2+_n][kk],                       \
                            acc[(mp)*2+_m][(np)*2+_n], 0, 0, 0);                \
        __builtin_amdgcn_s_setprio(0); } while (0)

    STGB(0); STGA(0); STGB(1); STGA(1);
    VMW6; CLOB; BARR; CLOB;

    for (int t = 0; t < NT; ++t) {
        int b = t & 1;
        int ab  = b * 8192  + (wm * 64 + col) * 64;
        int bbo = b * 16384 + (wn * 64 + col) * 64;
        RD_A(0); RD_B(0); RD_B(1);
        CLOB;
        MM(0, 0); MM(0, 1);
        CLOB; BARR; CLOB;
        RD_A(1);
        if (t + 2 < NT) STGB(t + 2);
        CLOB;
        MM(1, 1); MM(1, 0);
        if (t + 2 < NT) { STGA(t + 2); VMW6; }
        else if (t + 1 < NT) { VMW0; }
        CLOB; BARR;
    }
    #undef STG_HALF
    #undef STGA
    #undef STGB
    #undef RD_A
    #undef RD_B
    #undef MM

    #pragma unroll
    for (int mi = 0; mi < 4; ++mi) {
        int rbase = m0 + wm * 64 + mi * 16 + quad * 4;
        #pragma unroll
        for (int ni = 0; ni < 4; ++ni) {
            int cc = n0 + wn * 64 + ni * 16 + col;
            #pragma unroll
            for (int r = 0; r < 4; ++r)
                C[(long)(rbase + r) * ldc + cc] = (OutT)acc[mi][ni][r];
        }
    }
}

// ---------------- MFMA flash attention, v10 (R20-verified) ----------------
#define QS 72
#define C_SL 0.18033688011112042f   // 0.125 * log2(e)

__device__ __forceinline__ int vsw(int d, int k) {
    return d * 64 + ((((k >> 3) ^ (d & 7) ^ ((d >> 3) & 7)) & 7) << 3) + (k & 7);
}

__global__ __launch_bounds__(256)
void attn_mfma(bf16* __restrict__ qkv)
{
    __shared__ bf16 Ks[64 * QS];        //  9.2 KB
    __shared__ bf16 Vt[64 * 64];        //  8.0 KB (vsw-swizzled)
    __shared__ bf16 Ps[4 * 32 * QS];    // 18.4 KB
    const int T = 2048, D3 = 3072;
    int tid = threadIdx.x;
    int lane = tid & 63, wid = tid >> 6;
    int quad = lane >> 4, col = lane & 15;
    int bh = blockIdx.x & 63;
    int qt = 15 - (blockIdx.x >> 6);     // heavy tiles dispatched first
    int b = bh >> 4, h = bh & 15;
    long base = (long)b * T * D3 + h * 64;
    int q0 = qt * 128;
    int nk = 2 * qt + 2;
    int srow = tid >> 2, dseg = (tid & 3) * 16;     // K staging map (64x64)
    int kg4 = (tid >> 4) * 4, dg4 = (tid & 15) * 4; // V staging map (4k x 4d)
    bf16* Pw = &Ps[wid * 32 * QS];

    bf16x8 aq[2][2];
    #pragma unroll
    for (int nt = 0; nt < 2; ++nt) {
        const bf16* gq = &qkv[base + (long)(q0 + wid * 32 + nt * 16 + col) * D3 + quad * 8];
        aq[nt][0] = *(const bf16x8*)gq;
        aq[nt][1] = *(const bf16x8*)(gq + 32);
    }
    bf16 one1 = (bf16)1.0f;
    bf16x8 bones = {one1, one1, one1, one1, one1, one1, one1, one1};

    f4 of[2][4], lac[2];
    #pragma unroll
    for (int mg = 0; mg < 2; ++mg) {
        lac[mg] = (f4){0.f, 0.f, 0.f, 0.f};
        #pragma unroll
        for (int n = 0; n < 4; ++n) of[mg][n] = (f4){0.f, 0.f, 0.f, 0.f};
    }

    const bf16* g0 = &qkv[base + (long)srow * D3 + 1024 + dseg];
    bf16x8 kr0 = *(const bf16x8*)g0;
    bf16x8 kr1 = *(const bf16x8*)(g0 + 8);
    const bf16* gV = &qkv[base + (long)kg4 * D3 + 2048 + dg4];
    bf16x4 vr[4];
    #pragma unroll
    for (int j = 0; j < 4; ++j) vr[j] = *(const bf16x4*)(gV + (long)j * D3);

    for (int kt = 0; kt < nk; ++kt) {
        __syncthreads();
        *(bf16x8*)&Ks[srow * QS + dseg]     = kr0;
        *(bf16x8*)&Ks[srow * QS + dseg + 8] = kr1;
        #pragma unroll
        for (int i = 0; i < 4; ++i) {    // 4x4 in-register transpose
            bf16x4 c = { vr[0][i], vr[1][i], vr[2][i], vr[3][i] };
            *(bf16x4*)&Vt[vsw(dg4 + i, kg4)] = c;
        }
        if (kt + 1 < nk) {
            const bf16* gKn = &qkv[base + (long)((kt + 1) * 64 + srow) * D3 + 1024 + dseg];
            kr0 = *(const bf16x8*)gKn;
            kr1 = *(const bf16x8*)(gKn + 8);
            const bf16* gVn = &qkv[base + (long)((kt + 1) * 64 + kg4) * D3 + 2048 + dg4];
            #pragma unroll
            for (int j = 0; j < 4; ++j) vr[j] = *(const bf16x4*)(gVn + (long)j * D3);
        }
        __syncthreads();
        bool diag = (kt >= nk - 2);
        int k0 = kt * 64;
        #pragma unroll
        for (int mt = 0; mt < 4; ++mt) {
            bf16x8 ak0 = *(const bf16x8*)&Ks[(mt * 16 + col) * QS + quad * 8];
            bf16x8 ak1 = *(const bf16x8*)&Ks[(mt * 16 + col) * QS + 32 + quad * 8];
            #pragma unroll
            for (int nt = 0; nt < 2; ++nt) {
                f4 z = (f4){0.f, 0.f, 0.f, 0.f};
                __builtin_amdgcn_s_setprio(1);
                z = __builtin_amdgcn_mfma_f32_16x16x32_bf16(ak0, aq[nt][0], z, 0, 0, 0);
                f4 st = __builtin_amdgcn_mfma_f32_16x16x32_bf16(ak1, aq[nt][1], z, 0, 0, 0);
                __builtin_amdgcn_s_setprio(0);
                bf16x4 pk;
                if (diag) {
                    int qg = q0 + wid * 32 + nt * 16 + col;
                    #pragma unroll
                    for (int r = 0; r < 4; ++r) {
                        float arg = fmaf(st[r], C_SL, -16.f);
                        if ((k0 + mt * 16 + quad * 4 + r) > qg) arg = -1e30f;
                        pk[r] = (bf16)fast_exp2(arg);
                    }
                } else {
                    #pragma unroll
                    for (int r = 0; r < 4; ++r)
                        pk[r] = (bf16)fast_exp2(fmaf(st[r], C_SL, -16.f));
                }
                *(bf16x4*)&Pw[(nt * 16 + col) * QS + mt * 16 + quad * 4] = pk;
            }
        }
        bf16x8 ap[2][2];
        #pragma unroll
        for (int mg = 0; mg < 2; ++mg) {
            ap[mg][0] = *(const bf16x8*)&Pw[(mg * 16 + col) * QS + quad * 8];
            ap[mg][1] = *(const bf16x8*)&Pw[(mg * 16 + col) * QS + 32 + quad * 8];
        }
        #pragma unroll
        for (int nd = 0; nd < 4; ++nd) {
            bf16x8 bv0 = *(const bf16x8*)&Vt[vsw(nd * 16 + col, quad * 8)];
            bf16x8 bv1 = *(const bf16x8*)&Vt[vsw(nd * 16 + col, 32 + quad * 8)];
            __builtin_amdgcn_s_setprio(1);
            of[0][nd] = __builtin_amdgcn_mfma_f32_16x16x32_bf16(ap[0][0], bv0, of[0][nd], 0, 0, 0);
            of[0][nd] = __builtin_amdgcn_mfma_f32_16x16x32_bf16(ap[0][1], bv1, of[0][nd], 0, 0, 0);
            of[1][nd] = __builtin_amdgcn_mfma_f32_16x16x32_bf16(ap[1][0], bv0, of[1][nd], 0, 0, 0);
            of[1][nd] = __builtin_amdgcn_mfma_f32_16x16x32_bf16(ap[1][1], bv1, of[1][nd], 0, 0, 0);
            __builtin_amdgcn_s_setprio(0);
        }
        __builtin_amdgcn_s_setprio(1);
        #pragma unroll
        for (int mg = 0; mg < 2; ++mg) {
            lac[mg] = __builtin_amdgcn_mfma_f32_16x16x32_bf16(ap[mg][0], bones, lac[mg], 0, 0, 0);
            lac[mg] = __builtin_amdgcn_mfma_f32_16x16x32_bf16(ap[mg][1], bones, lac[mg], 0, 0, 0);
        }
        __builtin_amdgcn_s_setprio(0);
    }
    #pragma unroll
    for (int mg = 0; mg < 2; ++mg)
        #pragma unroll
        for (int r = 0; r < 4; ++r) {
            float inv = 1.f / lac[mg][r];
            long yoff = base + (long)(q0 + wid * 32 + mg * 16 + quad * 4 + r) * D3;
            #pragma unroll
            for (int nd = 0; nd < 4; ++nd)
                qkv[yoff + nd * 16 + col] = (bf16)(of[mg][nd][r] * inv);
        }
}

// --------------------------------------------------------------------------
extern "C" void kernel_launch(void* const* d_in, const int* in_sizes, int n_in,
                              void* d_out, int out_size, void* d_ws, size_t ws_size,
                              hipStream_t stream) {
    const float* x      = (const float*)d_in[0];  // [8192,1024] fp32
    const float* W_attn = (const float*)d_in[1];  // [1024,3072] fp32
    const float* W_proj = (const float*)d_in[2];  // [1024,1024] fp32
    float* out = (float*)d_out;                   // [8192,1024] fp32

    // ws layout (58.7 MB): qkv | WtA | WtP
    bf16* qkv = (bf16*)d_ws;                         // [8192,3072]  50.3 MB
    bf16* WtA = qkv + (size_t)8192 * 3072;           // [3072,1024]   6.3 MB
    bf16* WtP = WtA + (size_t)3072 * 1024;           // [1024,1024]   2.1 MB
    bf16* xb = (bf16*)d_out;   // bf16 x staged in d_out; dead before gemm2

    static bool attr_set = false;
    if (!attr_set) {
        hipFuncSetAttribute((const void*)gemm256sq,
                            hipFuncAttributeMaxDynamicSharedMemorySize, 131072);
        hipFuncSetAttribute((const void*)gemm256<float>,
                            hipFuncAttributeMaxDynamicSharedMemorySize, 98304);
        attr_set = true;
    }

    // fused prep: cast x (8192 blocks) + transpose W_attn (768) + W_proj (256)
    prep<<<9216, 256, 0, stream>>>(x, xb, W_attn, WtA, W_proj, WtP);
    // qkv = xb @ W_attn  (bf16 out): 256x256 8-phase, grid 12x32 = 384
    gemm256sq<<<dim3(12, 32), 512, 131072, stream>>>(xb, WtA, qkv,
                                                     1024, 1024, 3072, 1024);
    // MFMA flash attention; y written into qkv's Q columns
    attn_mfma<<<1024, 256, 0, stream>>>(qkv);
    // out = y @ W_proj: 128x256 tiles, grid 4x64 = 256 = exactly 1 wave
    gemm256<float><<<dim3(4, 64), 512, 98304, stream>>>(qkv, WtP, out,
                                                        3072, 1024, 1024, 1024);
}